// Round 19
// baseline (58.927 us; speedup 1.0000x reference)
//
#include <hip/hip_runtime.h>
#include <math.h>

#define LL 4096
#define CC 128
#define SS 64
#define CLEN 32    // steps per chunk (wave)
#define GW 8       // chunks (waves) per group/block
#define NG 16      // groups; NG*GW*CLEN = LL
#define CS 8192    // CC*SS
#define LOG2E 1.44269504088896f

// ---------------- kernel 1: projections (B, Cm, dtT) + xT (R12 verbatim) ----
__global__ __launch_bounds__(256) void k_proj(
    const float* __restrict__ x,
    const float* __restrict__ Bk, const float* __restrict__ Bb,
    const float* __restrict__ Ck, const float* __restrict__ Cb,
    const float* __restrict__ Dk, const float* __restrict__ Db,
    float* __restrict__ Bmat, float* __restrict__ Cmat,
    float* __restrict__ DTmT, float* __restrict__ xT)
{
    __shared__ float xs[CC][20];
    const int r0 = blockIdx.x * 16;
    const int t = threadIdx.x;
    {
        const int r = t >> 4, k8 = (t & 15) * 8;
        const float4 v0 = *(const float4*)&x[(r0 + r) * CC + k8];
        const float4 v1 = *(const float4*)&x[(r0 + r) * CC + k8 + 4];
        xs[k8+0][r] = v0.x; xs[k8+1][r] = v0.y; xs[k8+2][r] = v0.z; xs[k8+3][r] = v0.w;
        xs[k8+4][r] = v1.x; xs[k8+5][r] = v1.y; xs[k8+6][r] = v1.z; xs[k8+7][r] = v1.w;
    }
    __syncthreads();
    {   // emit x transposed [C][L]
        const int k = t >> 1, half = (t & 1) * 8;
        const float4 a = *(const float4*)&xs[k][half];
        const float4 b = *(const float4*)&xs[k][half + 4];
        *(float4*)&xT[k * LL + r0 + half]     = a;
        *(float4*)&xT[k * LL + r0 + half + 4] = b;
    }
    const int tc = t & 63, tr = t >> 6;
    const float* Wb; int wstride, wo;
    if (tc < 16)      { Wb = Bk; wstride = SS; wo = 4 * tc; }
    else if (tc < 32) { Wb = Ck; wstride = SS; wo = 4 * tc - 64; }
    else              { Wb = Dk; wstride = CC; wo = 4 * tc - 128; }
    float acc[4][4];
#pragma unroll
    for (int r = 0; r < 4; ++r)
#pragma unroll
        for (int j = 0; j < 4; ++j) acc[r][j] = 0.0f;
    for (int k = 0; k < CC; ++k) {
        const float4 wq = *(const float4*)(Wb + k * wstride + wo);
        const float4 xq = *(const float4*)&xs[k][4 * tr];
        const float wv[4] = {wq.x, wq.y, wq.z, wq.w};
        const float xv[4] = {xq.x, xq.y, xq.z, xq.w};
#pragma unroll
        for (int r = 0; r < 4; ++r)
#pragma unroll
            for (int j = 0; j < 4; ++j) acc[r][j] = fmaf(xv[r], wv[j], acc[r][j]);
    }
    const int rb = r0 + 4 * tr;
    if (tc < 32) {
        const float* bb = (tc < 16) ? Bb : Cb;
        const float add = (tc < 16) ? 1.0f : 0.0f;
        float bias[4];
#pragma unroll
        for (int j = 0; j < 4; ++j) bias[j] = add + bb[wo + j];
        float* dst = (tc < 16) ? Bmat : Cmat;
#pragma unroll
        for (int r = 0; r < 4; ++r) {
            const float4 o = make_float4(acc[r][0] + bias[0], acc[r][1] + bias[1],
                                         acc[r][2] + bias[2], acc[r][3] + bias[3]);
            *(float4*)&dst[(rb + r) * SS + wo] = o;
        }
    } else {
#pragma unroll
        for (int j = 0; j < 4; ++j) {
            const float bj = Db[wo + j] + 0.000244140625f;
            float sp[4];
#pragma unroll
            for (int r = 0; r < 4; ++r) {
                const float z = acc[r][j] + bj;
                sp[r] = fmaxf(z, 0.0f) + log1pf(__expf(-fabsf(z)));
            }
            *(float4*)&DTmT[(wo + j) * LL + rb] = make_float4(sp[0], sp[1], sp[2], sp[3]);
        }
    }
}

// ------- kernel 2: group aggregates (R12 verbatim) -------
__global__ __launch_bounds__(512, 4) void k_sweep1(
    const float* __restrict__ xT, const float* __restrict__ A_log,
    const float* __restrict__ Bmat, const float* __restrict__ DTmT,
    float2* __restrict__ GaGu)
{
    __shared__ float2 agg[GW][SS];
    const int lane = threadIdx.x & 63;
    const int w = __builtin_amdgcn_readfirstlane(threadIdx.x >> 6);
    const int c = blockIdx.x >> 4;          // SGPR
    const int g = blockIdx.x & (NG - 1);    // SGPR
    const int j = c * SS + lane;
    const float A = -__expf(A_log[j]);
    const float A2 = A * LOG2E;             // At = 2^(A2*dt)
    const float invA = 1.0f / A;
    const int l0 = (g * GW + w) * CLEN;
    const float* dtp = DTmT + c * LL + l0;
    const float* xp  = xT   + c * LL + l0;
    const float* Bp  = Bmat + l0 * SS + lane;
    float ap = 1.0f, uc = 0.0f;
#pragma unroll
    for (int i = 0; i < CLEN; ++i) {
        const float At = __builtin_amdgcn_exp2f(A2 * dtp[i]);
        const float u  = (At - 1.0f) * invA * (Bp[i * SS] * xp[i]);
        ap *= At;
        uc = fmaf(At, uc, u);
    }
    agg[w][lane] = make_float2(ap, uc);
    __syncthreads();
    if (w == 0) {
        float ga = 1.0f, gu = 0.0f;
#pragma unroll
        for (int k = 0; k < GW; ++k) {
            const float2 t = agg[k][lane];
            gu = fmaf(t.x, gu, t.y);
            ga *= t.x;
        }
        GaGu[g * CS + j] = make_float2(ga, gu);
    }
}

// ------- kernel 3: wave0-prologue + reg-cached rewalk + emit (R16 verbatim) --
__global__ __launch_bounds__(512) void k_emit(
    const float* __restrict__ xT, const float* __restrict__ A_log,
    const float* __restrict__ Bmat, const float* __restrict__ Cmat,
    const float* __restrict__ DTmT,
    const float2* __restrict__ GaGu,
    float* __restrict__ y)
{
    __shared__ float2 agg[GW][SS];
    __shared__ float hgs[SS];
    const int lane = threadIdx.x & 63;
    const int w = __builtin_amdgcn_readfirstlane(threadIdx.x >> 6);
    const int c = blockIdx.x >> 4;          // SGPR
    const int g = blockIdx.x & (NG - 1);    // SGPR
    const int j = c * SS + lane;
    const float A = -__expf(A_log[j]);
    const float A2 = A * LOG2E;
    const float invA = 1.0f / A;
    if (w == 0) {
        float hg = 0.0f;
        float2 ggr[NG - 1];
#pragma unroll
        for (int gg = 0; gg < NG - 1; ++gg) ggr[gg] = GaGu[gg * CS + j];
#pragma unroll
        for (int gg = 0; gg < NG - 1; ++gg)
            hg = (gg < g) ? fmaf(ggr[gg].x, hg, ggr[gg].y) : hg;
        hgs[lane] = hg;
    }
    const int l0 = (g * GW + w) * CLEN;
    const float* dtp = DTmT + c * LL + l0;
    const float* xp  = xT   + c * LL + l0;
    const float* Bp  = Bmat + l0 * SS + lane;
    const float* Cp  = Cmat + l0 * SS + lane;
    float at[CLEN], uu[CLEN];
    {
        float ap = 1.0f, uc = 0.0f;
#pragma unroll
        for (int i = 0; i < CLEN; ++i) {
            at[i] = __builtin_amdgcn_exp2f(A2 * dtp[i]);
            uu[i] = (at[i] - 1.0f) * invA * (Bp[i * SS] * xp[i]);
            ap *= at[i];
            uc = fmaf(at[i], uc, uu[i]);
        }
        agg[w][lane] = make_float2(ap, uc);
    }
    __syncthreads();
    const float hg = hgs[lane];
    float ea = 1.0f, eu = 0.0f;
    for (int k = 0; k < w; ++k) {
        const float2 t = agg[k][lane];
        eu = fmaf(t.x, eu, t.y);
        ea *= t.x;
    }
    float h = fmaf(ea, hg, eu);
#pragma unroll
    for (int i = 0; i < CLEN; ++i) {
        h = fmaf(at[i], h, uu[i]);
        uu[i] = Cp[i * SS] * h;
    }
#pragma unroll
    for (int k = 0; k < 5; ++k) {
        const int d = 1 << k;
        const bool hi = (lane & d) != 0;
#pragma unroll
        for (int i2 = 0; i2 < (CLEN >> (k + 1)); ++i2) {
            const float a = uu[2 * i2], b = uu[2 * i2 + 1];
            const float send = hi ? a : b;
            const float t = __shfl_xor(send, d, 64);
            uu[i2] = (hi ? b : a) + t;
        }
    }
    const float t = __shfl_xor(uu[0], 32, 64);
    const float yv = uu[0] + t;
    if (lane < 32) y[(l0 + lane) * CC + c] = yv;
}

extern "C" void kernel_launch(void* const* d_in, const int* in_sizes, int n_in,
                              void* d_out, int out_size, void* d_ws, size_t ws_size,
                              hipStream_t stream)
{
    const float* x  = (const float*)d_in[0];
    const float* Al = (const float*)d_in[1];
    const float* Bk = (const float*)d_in[2];
    const float* Bb = (const float*)d_in[3];
    const float* Ck = (const float*)d_in[4];
    const float* Cb = (const float*)d_in[5];
    const float* Dk = (const float*)d_in[6];
    const float* Db = (const float*)d_in[7];
    float* y  = (float*)d_out;
    float* ws = (float*)d_ws;

    float*  Bmat = ws;                        // [L][S]   1 MB
    float*  Cmat = Bmat + LL * SS;            // [L][S]   1 MB
    float*  DTmT = Cmat + LL * SS;            // [C][L]   2 MB
    float*  xT   = DTmT + CC * LL;            // [C][L]   2 MB
    float2* GaGu = (float2*)(xT + CC * LL);   // [NG][CS] 1 MB

    // DIAGNOSTIC: double-launch (idempotent) k_proj.
    // dur_R19 - dur_R16 = t(proj) + 1 launch gap.
    k_proj  <<<LL / 16, 256, 0, stream>>>(x, Bk, Bb, Ck, Cb, Dk, Db, Bmat, Cmat, DTmT, xT);
    k_proj  <<<LL / 16, 256, 0, stream>>>(x, Bk, Bb, Ck, Cb, Dk, Db, Bmat, Cmat, DTmT, xT);
    k_sweep1<<<CC * NG, 512, 0, stream>>>(xT, Al, Bmat, DTmT, GaGu);
    k_emit  <<<CC * NG, 512, 0, stream>>>(xT, Al, Bmat, Cmat, DTmT, GaGu, y);
}

// Round 20
// 46.966 us; speedup vs baseline: 1.2547x; 1.2547x over previous
//
#include <hip/hip_runtime.h>
#include <hip/hip_bf16.h>
#include <math.h>

#define LL 4096
#define CC 128
#define SS 64
#define CLEN 32    // steps per chunk (wave)
#define GW 8       // chunks (waves) per group/block
#define NG 16      // groups; NG*GW*CLEN = LL
#define CS 8192    // CC*SS
#define LOG2E 1.44269504088896f

typedef unsigned short u16;
struct u16x4 { u16 a, b, c, d; };

static __device__ __forceinline__ u16 f2bf(float f) {
    union { float f; unsigned u; } v; v.f = f;
    // round-to-nearest-even bf16
    unsigned r = v.u + 0x7fff + ((v.u >> 16) & 1);
    return (u16)(r >> 16);
}
static __device__ __forceinline__ float bf2f(u16 h) {
    union { unsigned u; float f; } v; v.u = ((unsigned)h) << 16;
    return v.f;
}

// ---------------- kernel 1: projections (B, Cm bf16; dtT) + xT ----------------
__global__ __launch_bounds__(256) void k_proj(
    const float* __restrict__ x,
    const float* __restrict__ Bk, const float* __restrict__ Bb,
    const float* __restrict__ Ck, const float* __restrict__ Cb,
    const float* __restrict__ Dk, const float* __restrict__ Db,
    u16* __restrict__ Bmat, u16* __restrict__ Cmat,
    float* __restrict__ DTmT, float* __restrict__ xT)
{
    __shared__ float xs[CC][20];
    const int r0 = blockIdx.x * 16;
    const int t = threadIdx.x;
    {
        const int r = t >> 4, k8 = (t & 15) * 8;
        const float4 v0 = *(const float4*)&x[(r0 + r) * CC + k8];
        const float4 v1 = *(const float4*)&x[(r0 + r) * CC + k8 + 4];
        xs[k8+0][r] = v0.x; xs[k8+1][r] = v0.y; xs[k8+2][r] = v0.z; xs[k8+3][r] = v0.w;
        xs[k8+4][r] = v1.x; xs[k8+5][r] = v1.y; xs[k8+6][r] = v1.z; xs[k8+7][r] = v1.w;
    }
    __syncthreads();
    {   // emit x transposed [C][L]
        const int k = t >> 1, half = (t & 1) * 8;
        const float4 a = *(const float4*)&xs[k][half];
        const float4 b = *(const float4*)&xs[k][half + 4];
        *(float4*)&xT[k * LL + r0 + half]     = a;
        *(float4*)&xT[k * LL + r0 + half + 4] = b;
    }
    const int tc = t & 63, tr = t >> 6;
    const float* Wb; int wstride, wo;
    if (tc < 16)      { Wb = Bk; wstride = SS; wo = 4 * tc; }
    else if (tc < 32) { Wb = Ck; wstride = SS; wo = 4 * tc - 64; }
    else              { Wb = Dk; wstride = CC; wo = 4 * tc - 128; }
    float acc[4][4];
#pragma unroll
    for (int r = 0; r < 4; ++r)
#pragma unroll
        for (int j = 0; j < 4; ++j) acc[r][j] = 0.0f;
    for (int k = 0; k < CC; ++k) {
        const float4 wq = *(const float4*)(Wb + k * wstride + wo);
        const float4 xq = *(const float4*)&xs[k][4 * tr];
        const float wv[4] = {wq.x, wq.y, wq.z, wq.w};
        const float xv[4] = {xq.x, xq.y, xq.z, xq.w};
#pragma unroll
        for (int r = 0; r < 4; ++r)
#pragma unroll
            for (int j = 0; j < 4; ++j) acc[r][j] = fmaf(xv[r], wv[j], acc[r][j]);
    }
    const int rb = r0 + 4 * tr;
    if (tc < 32) {
        const float* bb = (tc < 16) ? Bb : Cb;
        const float add = (tc < 16) ? 1.0f : 0.0f;
        float bias[4];
#pragma unroll
        for (int j = 0; j < 4; ++j) bias[j] = add + bb[wo + j];
        u16* dst = (tc < 16) ? Bmat : Cmat;
#pragma unroll
        for (int r = 0; r < 4; ++r) {
            u16x4 o;
            o.a = f2bf(acc[r][0] + bias[0]);
            o.b = f2bf(acc[r][1] + bias[1]);
            o.c = f2bf(acc[r][2] + bias[2]);
            o.d = f2bf(acc[r][3] + bias[3]);
            *(u16x4*)&dst[(rb + r) * SS + wo] = o;   // 8B store, aligned (wo%4==0)
        }
    } else {
#pragma unroll
        for (int j = 0; j < 4; ++j) {
            const float bj = Db[wo + j] + 0.000244140625f;
            float sp[4];
#pragma unroll
            for (int r = 0; r < 4; ++r) {
                const float z = acc[r][j] + bj;
                sp[r] = fmaxf(z, 0.0f) + log1pf(__expf(-fabsf(z)));
            }
            *(float4*)&DTmT[(wo + j) * LL + rb] = make_float4(sp[0], sp[1], sp[2], sp[3]);
        }
    }
}

// ------- kernel 2: group aggregates (bf16 B loads) -------
__global__ __launch_bounds__(512, 4) void k_sweep1(
    const float* __restrict__ xT, const float* __restrict__ A_log,
    const u16* __restrict__ Bmat, const float* __restrict__ DTmT,
    float2* __restrict__ GaGu)
{
    __shared__ float2 agg[GW][SS];
    const int lane = threadIdx.x & 63;
    const int w = __builtin_amdgcn_readfirstlane(threadIdx.x >> 6);
    const int c = blockIdx.x >> 4;          // SGPR
    const int g = blockIdx.x & (NG - 1);    // SGPR
    const int j = c * SS + lane;
    const float A = -__expf(A_log[j]);
    const float A2 = A * LOG2E;             // At = 2^(A2*dt)
    const float invA = 1.0f / A;
    const int l0 = (g * GW + w) * CLEN;
    const float* dtp = DTmT + c * LL + l0;
    const float* xp  = xT   + c * LL + l0;
    const u16*   Bp  = Bmat + l0 * SS + lane;
    float ap = 1.0f, uc = 0.0f;
#pragma unroll
    for (int i = 0; i < CLEN; ++i) {
        const float At = __builtin_amdgcn_exp2f(A2 * dtp[i]);
        const float u  = (At - 1.0f) * invA * (bf2f(Bp[i * SS]) * xp[i]);
        ap *= At;
        uc = fmaf(At, uc, u);
    }
    agg[w][lane] = make_float2(ap, uc);
    __syncthreads();
    if (w == 0) {
        float ga = 1.0f, gu = 0.0f;
#pragma unroll
        for (int k = 0; k < GW; ++k) {
            const float2 t = agg[k][lane];
            gu = fmaf(t.x, gu, t.y);
            ga *= t.x;
        }
        GaGu[g * CS + j] = make_float2(ga, gu);
    }
}

// ------- kernel 3: wave0-prologue + reg-cached rewalk + emit (bf16 B/C) ------
__global__ __launch_bounds__(512) void k_emit(
    const float* __restrict__ xT, const float* __restrict__ A_log,
    const u16* __restrict__ Bmat, const u16* __restrict__ Cmat,
    const float* __restrict__ DTmT,
    const float2* __restrict__ GaGu,
    float* __restrict__ y)
{
    __shared__ float2 agg[GW][SS];
    __shared__ float hgs[SS];
    const int lane = threadIdx.x & 63;
    const int w = __builtin_amdgcn_readfirstlane(threadIdx.x >> 6);
    const int c = blockIdx.x >> 4;          // SGPR
    const int g = blockIdx.x & (NG - 1);    // SGPR
    const int j = c * SS + lane;
    const float A = -__expf(A_log[j]);
    const float A2 = A * LOG2E;
    const float invA = 1.0f / A;
    if (w == 0) {
        float hg = 0.0f;
        float2 ggr[NG - 1];
#pragma unroll
        for (int gg = 0; gg < NG - 1; ++gg) ggr[gg] = GaGu[gg * CS + j];
#pragma unroll
        for (int gg = 0; gg < NG - 1; ++gg)
            hg = (gg < g) ? fmaf(ggr[gg].x, hg, ggr[gg].y) : hg;
        hgs[lane] = hg;
    }
    const int l0 = (g * GW + w) * CLEN;
    const float* dtp = DTmT + c * LL + l0;
    const float* xp  = xT   + c * LL + l0;
    const u16*   Bp  = Bmat + l0 * SS + lane;
    const u16*   Cp  = Cmat + l0 * SS + lane;
    float at[CLEN], uu[CLEN];
    {
        float ap = 1.0f, uc = 0.0f;
#pragma unroll
        for (int i = 0; i < CLEN; ++i) {
            at[i] = __builtin_amdgcn_exp2f(A2 * dtp[i]);
            uu[i] = (at[i] - 1.0f) * invA * (bf2f(Bp[i * SS]) * xp[i]);
            ap *= at[i];
            uc = fmaf(at[i], uc, uu[i]);
        }
        agg[w][lane] = make_float2(ap, uc);
    }
    __syncthreads();
    const float hg = hgs[lane];
    float ea = 1.0f, eu = 0.0f;
    for (int k = 0; k < w; ++k) {
        const float2 t = agg[k][lane];
        eu = fmaf(t.x, eu, t.y);
        ea *= t.x;
    }
    float h = fmaf(ea, hg, eu);
#pragma unroll
    for (int i = 0; i < CLEN; ++i) {
        h = fmaf(at[i], h, uu[i]);
        uu[i] = bf2f(Cp[i * SS]) * h;
    }
#pragma unroll
    for (int k = 0; k < 5; ++k) {
        const int d = 1 << k;
        const bool hi = (lane & d) != 0;
#pragma unroll
        for (int i2 = 0; i2 < (CLEN >> (k + 1)); ++i2) {
            const float a = uu[2 * i2], b = uu[2 * i2 + 1];
            const float send = hi ? a : b;
            const float t = __shfl_xor(send, d, 64);
            uu[i2] = (hi ? b : a) + t;
        }
    }
    const float t = __shfl_xor(uu[0], 32, 64);
    const float yv = uu[0] + t;
    if (lane < 32) y[(l0 + lane) * CC + c] = yv;
}

extern "C" void kernel_launch(void* const* d_in, const int* in_sizes, int n_in,
                              void* d_out, int out_size, void* d_ws, size_t ws_size,
                              hipStream_t stream)
{
    const float* x  = (const float*)d_in[0];
    const float* Al = (const float*)d_in[1];
    const float* Bk = (const float*)d_in[2];
    const float* Bb = (const float*)d_in[3];
    const float* Ck = (const float*)d_in[4];
    const float* Cb = (const float*)d_in[5];
    const float* Dk = (const float*)d_in[6];
    const float* Db = (const float*)d_in[7];
    float* y  = (float*)d_out;
    char* ws  = (char*)d_ws;

    u16*    Bmat = (u16*)ws;                       // [L][S] bf16  0.5 MB
    u16*    Cmat = Bmat + LL * SS;                 // [L][S] bf16  0.5 MB
    float*  DTmT = (float*)(Cmat + LL * SS);       // [C][L]       2 MB
    float*  xT   = DTmT + CC * LL;                 // [C][L]       2 MB
    float2* GaGu = (float2*)(xT + CC * LL);        // [NG][CS]     1 MB

    k_proj  <<<LL / 16, 256, 0, stream>>>(x, Bk, Bb, Ck, Cb, Dk, Db, Bmat, Cmat, DTmT, xT);
    k_sweep1<<<CC * NG, 512, 0, stream>>>(xT, Al, Bmat, DTmT, GaGu);
    k_emit  <<<CC * NG, 512, 0, stream>>>(xT, Al, Bmat, Cmat, DTmT, GaGu, y);
}